// Round 4
// baseline (165.210 us; speedup 1.0000x reference)
//
#include <hip/hip_runtime.h>
#include <hip/hip_cooperative_groups.h>

namespace cg = cooperative_groups;

#define N 6144
#define NTYPE 4
#define EPS_MIN 1.0f
#define EPS_MAX 5.0f
#define ALPHA 2.8f
#define R_CUTOFF 2.0f
#define R_ONSET 1.7f

constexpr int TILE_I = 256;             // threads per block = i-tile
constexpr int TILE_J = 96;              // j-tile per block -> grid 24x64 = 1536 = 6 blocks/CU exactly
constexpr int NIB = N / TILE_I;         // 24
constexpr int NJB = N / TILE_J;         // 64
constexpr int NPART = NIB * NJB;        // 1536 partial sums

constexpr float RC2 = R_CUTOFF * R_CUTOFF;              // 4.0
constexpr float RO2 = R_ONSET * R_ONSET;                // 2.89
constexpr float INV_DENOM = 1.0f / ((RC2 - RO2) * (RC2 - RO2) * (RC2 - RO2));

__device__ __forceinline__ float block_reduce_256(float v) {
    __shared__ float ws[4];
    #pragma unroll
    for (int off = 32; off > 0; off >>= 1) v += __shfl_down(v, off);
    const int lane = threadIdx.x & 63;
    const int wid  = threadIdx.x >> 6;
    if (lane == 0) ws[wid] = v;
    __syncthreads();
    if (wid == 0) {
        v = (lane < 4) ? ws[lane] : 0.0f;
        #pragma unroll
        for (int off = 2; off > 0; off >>= 1) v += __shfl_down(v, off);
    }
    return v;  // valid in thread 0
}

// Derive per-particle packed data straight from the inputs (L2-hot, ~300 KB total):
//   a = (x, y, z, radius)   b = (s, c_last, type_bits, unused)
__device__ __forceinline__ void derive(int idx,
                                       const float* __restrict__ pos,
                                       const float* __restrict__ celltype,
                                       const float* __restrict__ cadherin,
                                       const float* __restrict__ radius,
                                       float4& a, float4& b) {
    const float x = pos[idx * 3 + 0];
    const float y = pos[idx * 3 + 1];
    const float z = pos[idx * 3 + 2];
    const float r = radius[idx];
    float s = 0.0f;
    int   t = 0;
    float best = -1.0f;
    #pragma unroll
    for (int k = 0; k < NTYPE; ++k) {
        const float c = celltype[idx * NTYPE + k];
        s += c * cadherin[idx * (NTYPE + 1) + k];
        if (c > best) { best = c; t = k; }
    }
    const float clast = cadherin[idx * (NTYPE + 1) + NTYPE];
    a = make_float4(x, y, z, r);
    b = make_float4(s, clast, __int_as_float(t), 0.0f);
}

__global__ void __launch_bounds__(TILE_I, 6)
fused_kernel(const float* __restrict__ pos,
             const float* __restrict__ celltype,
             const float* __restrict__ cadherin,
             const float* __restrict__ radius,
             float* __restrict__ partial,
             float* __restrict__ out) {
    __shared__ float4 sA[TILE_J];
    __shared__ float4 sB[TILE_J];

    const int ib  = blockIdx.x;
    const int jb  = blockIdx.y;
    const int i   = ib * TILE_I + threadIdx.x;
    const int jg0 = jb * TILE_J;

    if (threadIdx.x < TILE_J) {
        float4 a, b;
        derive(jg0 + (int)threadIdx.x, pos, celltype, cadherin, radius, a, b);
        sA[threadIdx.x] = a;
        sB[threadIdx.x] = b;
    }
    float4 ai, bi;
    derive(i, pos, celltype, cadherin, radius, ai, bi);
    const int   ti = __float_as_int(bi.z);
    const float si = bi.x;

    __syncthreads();

    float acc = 0.0f;
    #pragma unroll 8
    for (int jj = 0; jj < TILE_J; ++jj) {
        const float4 aj = sA[jj];
        const float dx = ai.x - aj.x;
        const float dy = ai.y - aj.y;
        const float dz = ai.z - aj.z;
        const float dr2 = dx * dx + dy * dy + dz * dz;
        if (dr2 < RC2) {                      // r >= cutoff contributes exactly 0
            const float r = (dr2 > 0.0f) ? sqrtf(dr2) : 1.0f;  // diagonal included; removed below
            const float4 bj = sB[jj];
            const float sigma = ai.w + aj.w;
            const float e = __expf(-ALPHA * (r - sigma));
            const int   tj = __float_as_int(bj.z);
            float eps = (ti == tj) ? (si + bj.x) : (2.0f * bj.y);
            eps = EPS_MAX * eps + EPS_MIN;
            float cut;
            if (r < R_ONSET) {
                cut = 1.0f;
            } else {
                const float r2 = r * r;
                const float d  = RC2 - r2;
                cut = d * d * (RC2 + 2.0f * r2 - 3.0f * RO2) * INV_DENOM;
            }
            acc += eps * (e * e - 2.0f * e) * cut;
        }
    }

    // Subtract the self-interaction (computed above as the dr2==0 diagonal term):
    // r=1, cut=1, same-type eps; uses the same __expf so cancellation is ~exact.
    if ((unsigned)(i - jg0) < (unsigned)TILE_J) {
        const float sigma = ai.w + ai.w;
        const float e = __expf(-ALPHA * (1.0f - sigma));
        float eps = si + si;
        eps = EPS_MAX * eps + EPS_MIN;
        acc -= eps * (e * e - 2.0f * e);
    }

    const float bsum = block_reduce_256(acc);
    if (threadIdx.x == 0) partial[jb * NIB + ib] = bsum;

    __threadfence();              // make partials device-visible across XCDs
    cg::this_grid().sync();

    // Single block finishes the reduction in-kernel (deterministic order).
    if (ib == 0 && jb == 0) {
        float acc2 = 0.0f;
        #pragma unroll
        for (int k = threadIdx.x; k < NPART; k += TILE_I) acc2 += partial[k];
        const float total = block_reduce_256(acc2);
        if (threadIdx.x == 0) out[0] = 0.5f * total;
    }
}

extern "C" void kernel_launch(void* const* d_in, const int* in_sizes, int n_in,
                              void* d_out, int out_size, void* d_ws, size_t ws_size,
                              hipStream_t stream) {
    const float* pos      = (const float*)d_in[0];
    const float* celltype = (const float*)d_in[1];
    const float* cadherin = (const float*)d_in[2];
    const float* radius   = (const float*)d_in[3];
    float* out     = (float*)d_out;
    float* partial = (float*)d_ws;   // NPART floats

    void* args[] = {(void*)&pos, (void*)&celltype, (void*)&cadherin, (void*)&radius,
                    (void*)&partial, (void*)&out};
    dim3 grid(NIB, NJB);
    dim3 block(TILE_I);
    hipLaunchCooperativeKernel((void*)fused_kernel, grid, block, args, 0, stream);
}

// Round 5
// 39.072 us; speedup vs baseline: 4.2283x; 4.2283x over previous
//
#include <hip/hip_runtime.h>

#define N 6144
#define NTYPE 4
#define EPS_MIN 1.0f
#define EPS_MAX 5.0f
#define ALPHA 2.8f
#define R_CUTOFF 2.0f
#define R_ONSET 1.7f

constexpr int TILE_I = 256;             // threads per block = i-tile
constexpr int TILE_J = 96;              // j-tile per block -> grid 24x64 = 1536 = 6 blocks/CU exactly
constexpr int NIB = N / TILE_I;         // 24
constexpr int NJB = N / TILE_J;         // 64

constexpr float RC2 = R_CUTOFF * R_CUTOFF;              // 4.0
constexpr float RO2 = R_ONSET * R_ONSET;                // 2.89
constexpr float INV_DENOM = 1.0f / ((RC2 - RO2) * (RC2 - RO2) * (RC2 - RO2));

__device__ __forceinline__ float block_reduce_256(float v) {
    __shared__ float ws[4];
    #pragma unroll
    for (int off = 32; off > 0; off >>= 1) v += __shfl_down(v, off);
    const int lane = threadIdx.x & 63;
    const int wid  = threadIdx.x >> 6;
    if (lane == 0) ws[wid] = v;
    __syncthreads();
    if (wid == 0) {
        v = (lane < 4) ? ws[lane] : 0.0f;
        #pragma unroll
        for (int off = 2; off > 0; off >>= 1) v += __shfl_down(v, off);
    }
    return v;  // valid in thread 0
}

// Derive per-particle packed data straight from the inputs (L2-hot, ~300 KB total):
//   a = (x, y, z, radius)   b = (s, c_last, type_bits, unused)
__device__ __forceinline__ void derive(int idx,
                                       const float* __restrict__ pos,
                                       const float* __restrict__ celltype,
                                       const float* __restrict__ cadherin,
                                       const float* __restrict__ radius,
                                       float4& a, float4& b) {
    const float x = pos[idx * 3 + 0];
    const float y = pos[idx * 3 + 1];
    const float z = pos[idx * 3 + 2];
    const float r = radius[idx];
    float s = 0.0f;
    int   t = 0;
    float best = -1.0f;
    #pragma unroll
    for (int k = 0; k < NTYPE; ++k) {
        const float c = celltype[idx * NTYPE + k];
        s += c * cadherin[idx * (NTYPE + 1) + k];
        if (c > best) { best = c; t = k; }
    }
    const float clast = cadherin[idx * (NTYPE + 1) + NTYPE];
    a = make_float4(x, y, z, r);
    b = make_float4(s, clast, __int_as_float(t), 0.0f);
}

__global__ void __launch_bounds__(TILE_I)
pair_kernel(const float* __restrict__ pos,
            const float* __restrict__ celltype,
            const float* __restrict__ cadherin,
            const float* __restrict__ radius,
            float* __restrict__ out) {
    __shared__ float4 sA[TILE_J];
    __shared__ float4 sB[TILE_J];

    const int ib  = blockIdx.x;
    const int jb  = blockIdx.y;
    const int i   = ib * TILE_I + threadIdx.x;
    const int jg0 = jb * TILE_J;

    if (threadIdx.x < TILE_J) {
        float4 a, b;
        derive(jg0 + (int)threadIdx.x, pos, celltype, cadherin, radius, a, b);
        sA[threadIdx.x] = a;
        sB[threadIdx.x] = b;
    }
    float4 ai, bi;
    derive(i, pos, celltype, cadherin, radius, ai, bi);
    const int   ti = __float_as_int(bi.z);
    const float si = bi.x;

    __syncthreads();

    float acc = 0.0f;
    #pragma unroll 8
    for (int jj = 0; jj < TILE_J; ++jj) {
        const float4 aj = sA[jj];
        const float dx = ai.x - aj.x;
        const float dy = ai.y - aj.y;
        const float dz = ai.z - aj.z;
        const float dr2 = dx * dx + dy * dy + dz * dz;
        if (dr2 < RC2) {                      // r >= cutoff contributes exactly 0
            const float r = (dr2 > 0.0f) ? sqrtf(dr2) : 1.0f;  // diagonal included; removed below
            const float4 bj = sB[jj];
            const float sigma = ai.w + aj.w;
            const float e = __expf(-ALPHA * (r - sigma));
            const int   tj = __float_as_int(bj.z);
            float eps = (ti == tj) ? (si + bj.x) : (2.0f * bj.y);
            eps = EPS_MAX * eps + EPS_MIN;
            float cut;
            if (r < R_ONSET) {
                cut = 1.0f;
            } else {
                const float r2 = r * r;
                const float d  = RC2 - r2;
                cut = d * d * (RC2 + 2.0f * r2 - 3.0f * RO2) * INV_DENOM;
            }
            acc += eps * (e * e - 2.0f * e) * cut;
        }
    }

    // Subtract the self-interaction (computed above as the dr2==0 diagonal term):
    // r=1, cut=1, same-type eps; uses the same __expf so cancellation is ~exact.
    if ((unsigned)(i - jg0) < (unsigned)TILE_J) {
        const float sigma = ai.w + ai.w;
        const float e = __expf(-ALPHA * (1.0f - sigma));
        float eps = si + si;
        eps = EPS_MAX * eps + EPS_MIN;
        acc -= eps * (e * e - 2.0f * e);
    }

    const float bsum = block_reduce_256(acc);
    // One device-scope atomic per block; d_out was zeroed by the memset node
    // in this same graph, so replays never accumulate stale state.
    if (threadIdx.x == 0) atomicAdd(out, 0.5f * bsum);
}

extern "C" void kernel_launch(void* const* d_in, const int* in_sizes, int n_in,
                              void* d_out, int out_size, void* d_ws, size_t ws_size,
                              hipStream_t stream) {
    const float* pos      = (const float*)d_in[0];
    const float* celltype = (const float*)d_in[1];
    const float* cadherin = (const float*)d_in[2];
    const float* radius   = (const float*)d_in[3];
    float* out = (float*)d_out;

    hipMemsetAsync(out, 0, sizeof(float), stream);   // cheap graph node, re-zeroes every replay
    dim3 grid(NIB, NJB);
    pair_kernel<<<grid, TILE_I, 0, stream>>>(pos, celltype, cadherin, radius, out);
}

// Round 6
// 30.337 us; speedup vs baseline: 5.4459x; 1.2880x over previous
//
#include <hip/hip_runtime.h>

#define N 6144
#define NTYPE 4
#define EPS_MIN 1.0f
#define EPS_MAX 5.0f
#define ALPHA 2.8f
#define R_CUTOFF 2.0f
#define R_ONSET 1.7f

typedef float f32x2 __attribute__((ext_vector_type(2)));

constexpr int TILE_I = 256;             // threads per block = i-tile
constexpr int TILE_J = 96;              // j-tile per block -> grid 24x64 = 1536 = 6 blocks/CU
constexpr int NIB = N / TILE_I;         // 24
constexpr int NJB = N / TILE_J;         // 64
constexpr int NPART = NIB * NJB;        // 1536 partial sums

constexpr float RC2 = R_CUTOFF * R_CUTOFF;              // 4.0
constexpr float RO2 = R_ONSET * R_ONSET;                // 2.89
constexpr float INV_DENOM = 1.0f / ((RC2 - RO2) * (RC2 - RO2) * (RC2 - RO2));

__device__ __forceinline__ float block_reduce_256(float v) {
    __shared__ float ws[4];
    #pragma unroll
    for (int off = 32; off > 0; off >>= 1) v += __shfl_down(v, off);
    const int lane = threadIdx.x & 63;
    const int wid  = threadIdx.x >> 6;
    if (lane == 0) ws[wid] = v;
    __syncthreads();
    if (wid == 0) {
        v = (lane < 4) ? ws[lane] : 0.0f;
        #pragma unroll
        for (int off = 2; off > 0; off >>= 1) v += __shfl_down(v, off);
    }
    return v;  // valid in thread 0
}

// Derive per-particle data straight from the inputs (L2-hot, ~300 KB total).
__device__ __forceinline__ void derive(int idx,
                                       const float* __restrict__ pos,
                                       const float* __restrict__ celltype,
                                       const float* __restrict__ cadherin,
                                       const float* __restrict__ radius,
                                       float& x, float& y, float& z, float& rad,
                                       float& s, float& clast, int& t) {
    x   = pos[idx * 3 + 0];
    y   = pos[idx * 3 + 1];
    z   = pos[idx * 3 + 2];
    rad = radius[idx];
    const float4 ct = *reinterpret_cast<const float4*>(celltype + idx * NTYPE);
    s = ct.x * cadherin[idx * (NTYPE + 1) + 0]
      + ct.y * cadherin[idx * (NTYPE + 1) + 1]
      + ct.z * cadherin[idx * (NTYPE + 1) + 2]
      + ct.w * cadherin[idx * (NTYPE + 1) + 3];
    clast = cadherin[idx * (NTYPE + 1) + NTYPE];
    // one-hot -> type index
    t = 0;
    if (ct.y > 0.5f) t = 1;
    if (ct.z > 0.5f) t = 2;
    if (ct.w > 0.5f) t = 3;
}

// Rare hit-path: full Morse + smooth cutoff for one pair.
__device__ __forceinline__ float pair_term(float d2, float radi, int ti, float si,
                                           float radj, int tj, float sj, float clj) {
    const float r = (d2 > 0.0f) ? sqrtf(d2) : 1.0f;   // safe sqrt (diagonal -> r=1)
    const float sigma = radi + radj;
    const float e = __expf(-ALPHA * (r - sigma));
    float eps = (ti == tj) ? (si + sj) : (2.0f * clj);
    eps = EPS_MAX * eps + EPS_MIN;
    float cut;
    if (r < R_ONSET) {
        cut = 1.0f;
    } else {
        const float r2 = r * r;
        const float d  = RC2 - r2;
        cut = d * d * (RC2 + 2.0f * r2 - 3.0f * RO2) * INV_DENOM;
    }
    return eps * (e * e - 2.0f * e) * cut;
}

__global__ void __launch_bounds__(TILE_I)
pair_kernel(const float* __restrict__ pos,
            const float* __restrict__ celltype,
            const float* __restrict__ cadherin,
            const float* __restrict__ radius,
            float* __restrict__ partial) {
    // Pair-transposed hot data: sP = {x0,x1,y0,y1, x2,x3,y2,y3, ...}, sQ = {z0,z1,...}
    __shared__ __align__(16) float sP[2 * TILE_J];
    __shared__ __align__(8)  float sQ[TILE_J];
    // Cold (hit-path) data, scalar indexed
    __shared__ float sRad[TILE_J], sS[TILE_J], sCl[TILE_J];
    __shared__ int   sT[TILE_J];

    const int ib  = blockIdx.x;
    const int jb  = blockIdx.y;
    const int i   = ib * TILE_I + threadIdx.x;
    const int jg0 = jb * TILE_J;

    if (threadIdx.x < TILE_J) {
        float x, y, z, rad, s, cl; int t;
        derive(jg0 + (int)threadIdx.x, pos, celltype, cadherin, radius, x, y, z, rad, s, cl, t);
        const int k = threadIdx.x >> 1, h = threadIdx.x & 1;
        sP[4 * k + h]     = x;
        sP[4 * k + 2 + h] = y;
        sQ[threadIdx.x]   = z;
        sRad[threadIdx.x] = rad;
        sS[threadIdx.x]   = s;
        sCl[threadIdx.x]  = cl;
        sT[threadIdx.x]   = t;
    }
    float xi, yi, zi, rad_i, si, cl_i; int ti;
    derive(i, pos, celltype, cadherin, radius, xi, yi, zi, rad_i, si, cl_i, ti);

    __syncthreads();

    const f32x2 xi2 = {xi, xi}, yi2 = {yi, yi}, zi2 = {zi, zi};
    float acc = 0.0f;
    #pragma unroll 8
    for (int jj = 0; jj < TILE_J; jj += 2) {
        const f32x2 xj = *reinterpret_cast<const f32x2*>(&sP[2 * jj]);
        const f32x2 yj = *reinterpret_cast<const f32x2*>(&sP[2 * jj + 2]);
        const f32x2 zj = *reinterpret_cast<const f32x2*>(&sQ[jj]);
        const f32x2 dx = xi2 - xj;
        const f32x2 dy = yi2 - yj;
        const f32x2 dz = zi2 - zj;
        const f32x2 d2 = dx * dx + dy * dy + dz * dz;   // v_pk_mul + 2x v_pk_fma
        if (fminf(d2.x, d2.y) < RC2) {                  // r >= cutoff contributes exactly 0
            if (d2.x < RC2)
                acc += pair_term(d2.x, rad_i, ti, si, sRad[jj], sT[jj], sS[jj], sCl[jj]);
            if (d2.y < RC2)
                acc += pair_term(d2.y, rad_i, ti, si, sRad[jj + 1], sT[jj + 1], sS[jj + 1], sCl[jj + 1]);
        }
    }

    // Subtract the self-interaction (computed above as the dr2==0 diagonal term):
    // r=1, cut=1, same-type eps; identical expression -> ~exact cancellation.
    if ((unsigned)(i - jg0) < (unsigned)TILE_J) {
        const float sigma = rad_i + rad_i;
        const float e = __expf(-ALPHA * (1.0f - sigma));
        float eps = si + si;
        eps = EPS_MAX * eps + EPS_MIN;
        acc -= eps * (e * e - 2.0f * e);
    }

    const float bsum = block_reduce_256(acc);
    if (threadIdx.x == 0) partial[jb * NIB + ib] = bsum;
}

__global__ void __launch_bounds__(64)
final_reduce_kernel(const float* __restrict__ partial, float* __restrict__ out) {
    float acc = 0.0f;
    #pragma unroll
    for (int k = threadIdx.x; k < NPART; k += 64) acc += partial[k];
    #pragma unroll
    for (int off = 32; off > 0; off >>= 1) acc += __shfl_down(acc, off);
    if (threadIdx.x == 0) out[0] = 0.5f * acc;
}

extern "C" void kernel_launch(void* const* d_in, const int* in_sizes, int n_in,
                              void* d_out, int out_size, void* d_ws, size_t ws_size,
                              hipStream_t stream) {
    const float* pos      = (const float*)d_in[0];
    const float* celltype = (const float*)d_in[1];
    const float* cadherin = (const float*)d_in[2];
    const float* radius   = (const float*)d_in[3];
    float* out     = (float*)d_out;
    float* partial = (float*)d_ws;   // NPART floats

    dim3 grid(NIB, NJB);
    pair_kernel<<<grid, TILE_I, 0, stream>>>(pos, celltype, cadherin, radius, partial);
    final_reduce_kernel<<<1, 64, 0, stream>>>(partial, out);
}

// Round 7
// 28.592 us; speedup vs baseline: 5.7782x; 1.0610x over previous
//
#include <hip/hip_runtime.h>

#define N 6144
#define NTYPE 4
#define EPS_MIN 1.0f
#define EPS_MAX 5.0f
#define ALPHA 2.8f
#define R_CUTOFF 2.0f
#define R_ONSET 1.7f

constexpr int TILE_I = 256;             // threads per block = i-tile
constexpr int TILE_J = 96;              // j-tile per block -> grid 24x64 = 1536 = 6 blocks/CU exactly
constexpr int NIB = N / TILE_I;         // 24
constexpr int NJB = N / TILE_J;         // 64
constexpr int NPART = NIB * NJB;        // 1536 partial sums

constexpr float RC2 = R_CUTOFF * R_CUTOFF;              // 4.0
constexpr float RO2 = R_ONSET * R_ONSET;                // 2.89
constexpr float INV_DENOM = 1.0f / ((RC2 - RO2) * (RC2 - RO2) * (RC2 - RO2));

__device__ __forceinline__ float block_reduce_256(float v) {
    __shared__ float ws[4];
    #pragma unroll
    for (int off = 32; off > 0; off >>= 1) v += __shfl_down(v, off);
    const int lane = threadIdx.x & 63;
    const int wid  = threadIdx.x >> 6;
    if (lane == 0) ws[wid] = v;
    __syncthreads();
    if (wid == 0) {
        v = (lane < 4) ? ws[lane] : 0.0f;
        #pragma unroll
        for (int off = 2; off > 0; off >>= 1) v += __shfl_down(v, off);
    }
    return v;  // valid in thread 0
}

// Derive per-particle packed data straight from the inputs (L2-hot, ~300 KB total):
//   a = (x, y, z, radius)   b = (s, c_last, type_bits, unused)
__device__ __forceinline__ void derive(int idx,
                                       const float* __restrict__ pos,
                                       const float* __restrict__ celltype,
                                       const float* __restrict__ cadherin,
                                       const float* __restrict__ radius,
                                       float4& a, float4& b) {
    const float x = pos[idx * 3 + 0];
    const float y = pos[idx * 3 + 1];
    const float z = pos[idx * 3 + 2];
    const float r = radius[idx];
    float s = 0.0f;
    int   t = 0;
    float best = -1.0f;
    #pragma unroll
    for (int k = 0; k < NTYPE; ++k) {
        const float c = celltype[idx * NTYPE + k];
        s += c * cadherin[idx * (NTYPE + 1) + k];
        if (c > best) { best = c; t = k; }
    }
    const float clast = cadherin[idx * (NTYPE + 1) + NTYPE];
    a = make_float4(x, y, z, r);
    b = make_float4(s, clast, __int_as_float(t), 0.0f);
}

__global__ void __launch_bounds__(TILE_I)
pair_kernel(const float* __restrict__ pos,
            const float* __restrict__ celltype,
            const float* __restrict__ cadherin,
            const float* __restrict__ radius,
            float* __restrict__ partial) {
    __shared__ float4 sA[TILE_J];
    __shared__ float4 sB[TILE_J];

    const int ib  = blockIdx.x;
    const int jb  = blockIdx.y;
    const int i   = ib * TILE_I + threadIdx.x;
    const int jg0 = jb * TILE_J;

    if (threadIdx.x < TILE_J) {
        float4 a, b;
        derive(jg0 + (int)threadIdx.x, pos, celltype, cadherin, radius, a, b);
        sA[threadIdx.x] = a;
        sB[threadIdx.x] = b;
    }
    float4 ai, bi;
    derive(i, pos, celltype, cadherin, radius, ai, bi);
    const int   ti = __float_as_int(bi.z);
    const float si = bi.x;

    __syncthreads();

    float acc = 0.0f;
    #pragma unroll 8
    for (int jj = 0; jj < TILE_J; ++jj) {
        const float4 aj = sA[jj];
        const float dx = ai.x - aj.x;
        const float dy = ai.y - aj.y;
        const float dz = ai.z - aj.z;
        const float dr2 = dx * dx + dy * dy + dz * dz;
        if (dr2 < RC2) {                      // r >= cutoff contributes exactly 0
            const float r = (dr2 > 0.0f) ? sqrtf(dr2) : 1.0f;  // diagonal included; removed below
            const float4 bj = sB[jj];
            const float sigma = ai.w + aj.w;
            const float e = __expf(-ALPHA * (r - sigma));
            const int   tj = __float_as_int(bj.z);
            float eps = (ti == tj) ? (si + bj.x) : (2.0f * bj.y);
            eps = EPS_MAX * eps + EPS_MIN;
            float cut;
            if (r < R_ONSET) {
                cut = 1.0f;
            } else {
                const float r2 = r * r;
                const float d  = RC2 - r2;
                cut = d * d * (RC2 + 2.0f * r2 - 3.0f * RO2) * INV_DENOM;
            }
            acc += eps * (e * e - 2.0f * e) * cut;
        }
    }

    // Subtract the self-interaction (computed above as the dr2==0 diagonal term):
    // r=1, cut=1, same-type eps; uses the same __expf so cancellation is ~exact.
    if ((unsigned)(i - jg0) < (unsigned)TILE_J) {
        const float sigma = ai.w + ai.w;
        const float e = __expf(-ALPHA * (1.0f - sigma));
        float eps = si + si;
        eps = EPS_MAX * eps + EPS_MIN;
        acc -= eps * (e * e - 2.0f * e);
    }

    const float bsum = block_reduce_256(acc);
    if (threadIdx.x == 0) partial[jb * NIB + ib] = bsum;
}

__global__ void __launch_bounds__(256)
final_reduce_kernel(const float* __restrict__ partial, float* __restrict__ out) {
    float acc = 0.0f;
    #pragma unroll
    for (int k = threadIdx.x; k < NPART; k += 256) acc += partial[k];
    const float total = block_reduce_256(acc);
    if (threadIdx.x == 0) out[0] = 0.5f * total;
}

extern "C" void kernel_launch(void* const* d_in, const int* in_sizes, int n_in,
                              void* d_out, int out_size, void* d_ws, size_t ws_size,
                              hipStream_t stream) {
    const float* pos      = (const float*)d_in[0];
    const float* celltype = (const float*)d_in[1];
    const float* cadherin = (const float*)d_in[2];
    const float* radius   = (const float*)d_in[3];
    float* out     = (float*)d_out;
    float* partial = (float*)d_ws;   // NPART floats

    dim3 grid(NIB, NJB);
    pair_kernel<<<grid, TILE_I, 0, stream>>>(pos, celltype, cadherin, radius, partial);
    final_reduce_kernel<<<1, 256, 0, stream>>>(partial, out);
}

// Round 8
// 27.096 us; speedup vs baseline: 6.0971x; 1.0552x over previous
//
#include <hip/hip_runtime.h>

#define N 6144
#define NTYPE 4
#define EPS_MIN 1.0f
#define EPS_MAX 5.0f
#define ALPHA 2.8f
#define R_CUTOFF 2.0f
#define R_ONSET 1.7f

constexpr int TILE_I = 256;             // threads per block = i-tile
constexpr int TILE_J = 96;              // j-tile per block -> grid 24x64 = 1536 blocks
constexpr int NIB = N / TILE_I;         // 24
constexpr int NJB = N / TILE_J;         // 64
constexpr int NPART = NIB * NJB;        // 1536 slots

constexpr unsigned MAGIC = 0x5F3759DFu; // tag: != 0xAAAAAAAA poison, != 0 fresh-alloc

constexpr float RC2 = R_CUTOFF * R_CUTOFF;              // 4.0
constexpr float RO2 = R_ONSET * R_ONSET;                // 2.89
constexpr float INV_DENOM = 1.0f / ((RC2 - RO2) * (RC2 - RO2) * (RC2 - RO2));

__device__ __forceinline__ float block_reduce_256(float v) {
    __shared__ float ws[4];
    #pragma unroll
    for (int off = 32; off > 0; off >>= 1) v += __shfl_down(v, off);
    const int lane = threadIdx.x & 63;
    const int wid  = threadIdx.x >> 6;
    if (lane == 0) ws[wid] = v;
    __syncthreads();
    if (wid == 0) {
        v = (lane < 4) ? ws[lane] : 0.0f;
        #pragma unroll
        for (int off = 2; off > 0; off >>= 1) v += __shfl_down(v, off);
    }
    return v;  // valid in thread 0
}

// Derive per-particle packed data straight from the inputs (L2-hot, ~300 KB total):
//   a = (x, y, z, radius)   b = (s, c_last, type_bits, unused)
__device__ __forceinline__ void derive(int idx,
                                       const float* __restrict__ pos,
                                       const float* __restrict__ celltype,
                                       const float* __restrict__ cadherin,
                                       const float* __restrict__ radius,
                                       float4& a, float4& b) {
    const float x = pos[idx * 3 + 0];
    const float y = pos[idx * 3 + 1];
    const float z = pos[idx * 3 + 2];
    const float r = radius[idx];
    float s = 0.0f;
    int   t = 0;
    float best = -1.0f;
    #pragma unroll
    for (int k = 0; k < NTYPE; ++k) {
        const float c = celltype[idx * NTYPE + k];
        s += c * cadherin[idx * (NTYPE + 1) + k];
        if (c > best) { best = c; t = k; }
    }
    const float clast = cadherin[idx * (NTYPE + 1) + NTYPE];
    a = make_float4(x, y, z, r);
    b = make_float4(s, clast, __int_as_float(t), 0.0f);
}

// __launch_bounds__(256, 8): force VGPR <= 64 so 8 blocks/CU are resident ->
// 2048 slots >= 1536 blocks -> whole grid co-resident -> consumer spin cannot deadlock.
__global__ void __launch_bounds__(TILE_I, 8)
fused_kernel(const float* __restrict__ pos,
             const float* __restrict__ celltype,
             const float* __restrict__ cadherin,
             const float* __restrict__ radius,
             unsigned long long* __restrict__ slots,
             float* __restrict__ out) {
    __shared__ float4 sA[TILE_J];
    __shared__ float4 sB[TILE_J];

    const int ib  = blockIdx.x;
    const int jb  = blockIdx.y;
    const int i   = ib * TILE_I + threadIdx.x;
    const int jg0 = jb * TILE_J;

    if (threadIdx.x < TILE_J) {
        float4 a, b;
        derive(jg0 + (int)threadIdx.x, pos, celltype, cadherin, radius, a, b);
        sA[threadIdx.x] = a;
        sB[threadIdx.x] = b;
    }
    float4 ai, bi;
    derive(i, pos, celltype, cadherin, radius, ai, bi);
    const int   ti = __float_as_int(bi.z);
    const float si = bi.x;

    __syncthreads();

    float acc = 0.0f;
    #pragma unroll 8
    for (int jj = 0; jj < TILE_J; ++jj) {
        const float4 aj = sA[jj];
        const float dx = ai.x - aj.x;
        const float dy = ai.y - aj.y;
        const float dz = ai.z - aj.z;
        const float dr2 = dx * dx + dy * dy + dz * dz;
        if (dr2 < RC2) {                      // r >= cutoff contributes exactly 0
            const float r = (dr2 > 0.0f) ? sqrtf(dr2) : 1.0f;  // diagonal included; removed below
            const float4 bj = sB[jj];
            const float sigma = ai.w + aj.w;
            const float e = __expf(-ALPHA * (r - sigma));
            const int   tj = __float_as_int(bj.z);
            float eps = (ti == tj) ? (si + bj.x) : (2.0f * bj.y);
            eps = EPS_MAX * eps + EPS_MIN;
            float cut;
            if (r < R_ONSET) {
                cut = 1.0f;
            } else {
                const float r2 = r * r;
                const float d  = RC2 - r2;
                cut = d * d * (RC2 + 2.0f * r2 - 3.0f * RO2) * INV_DENOM;
            }
            acc += eps * (e * e - 2.0f * e) * cut;
        }
    }

    // Subtract the self-interaction (computed above as the dr2==0 diagonal term):
    // r=1, cut=1, same-type eps; identical expression -> ~exact cancellation.
    if ((unsigned)(i - jg0) < (unsigned)TILE_J) {
        const float sigma = ai.w + ai.w;
        const float e = __expf(-ALPHA * (1.0f - sigma));
        float eps = si + si;
        eps = EPS_MAX * eps + EPS_MIN;
        acc -= eps * (e * e - 2.0f * e);
    }

    const float bsum = block_reduce_256(acc);

    // Producer: publish (tag | payload) in ONE device-scope 64-bit atomic.
    // Tag+data travel together, so no separate fence/ordering is needed.
    const int b = jb * NIB + ib;
    if (threadIdx.x == 0) {
        const unsigned long long packed =
            ((unsigned long long)MAGIC << 32) | (unsigned long long)__float_as_uint(bsum);
        atomicExch(&slots[b], packed);
    }

    // Consumer: block (0,0) gathers all slots, then self-cleans them to 0.
    if (ib == 0 && jb == 0) {
        __syncthreads();   // keep block_reduce's shared ws safe before reuse below
        float acc2 = 0.0f;
        for (int k = threadIdx.x; k < NPART; k += TILE_I) {
            unsigned long long v;
            int guard = 0;
            do {
                v = atomicAdd(&slots[k], 0ull);   // device-coherent read
            } while ((unsigned)(v >> 32) != MAGIC && ++guard < (1 << 24));
            acc2 += __uint_as_float((unsigned)v);
            atomicExch(&slots[k], 0ull);          // reset for the next call
        }
        const float total = block_reduce_256(acc2);
        if (threadIdx.x == 0) out[0] = 0.5f * total;
    }
}

extern "C" void kernel_launch(void* const* d_in, const int* in_sizes, int n_in,
                              void* d_out, int out_size, void* d_ws, size_t ws_size,
                              hipStream_t stream) {
    const float* pos      = (const float*)d_in[0];
    const float* celltype = (const float*)d_in[1];
    const float* cadherin = (const float*)d_in[2];
    const float* radius   = (const float*)d_in[3];
    float* out = (float*)d_out;
    unsigned long long* slots = (unsigned long long*)d_ws;   // NPART x u64

    dim3 grid(NIB, NJB);
    fused_kernel<<<grid, TILE_I, 0, stream>>>(pos, celltype, cadherin, radius, slots, out);
}

// Round 9
// 26.927 us; speedup vs baseline: 6.1356x; 1.0063x over previous
//
#include <hip/hip_runtime.h>

#define N 6144
#define NTYPE 4
#define EPS_MIN 1.0f
#define EPS_MAX 5.0f
#define ALPHA 2.8f
#define R_CUTOFF 2.0f
#define R_ONSET 1.7f

constexpr int TILE_I = 256;             // threads per block = i-tile
constexpr int TILE_J = 96;              // j-tile per block -> grid 24x64 = 1536 blocks
constexpr int NIB = N / TILE_I;         // 24
constexpr int NJB = N / TILE_J;         // 64
constexpr int NPART = NIB * NJB;        // 1536 slots

constexpr unsigned MAGIC = 0x5F3759DFu; // tag: != 0xAAAAAAAA poison, != 0 fresh-alloc/cleaned

constexpr float RC2 = R_CUTOFF * R_CUTOFF;              // 4.0
constexpr float RO2 = R_ONSET * R_ONSET;                // 2.89
constexpr float INV_DENOM = 1.0f / ((RC2 - RO2) * (RC2 - RO2) * (RC2 - RO2));

__device__ __forceinline__ float block_reduce_256(float v) {
    __shared__ float ws[4];
    #pragma unroll
    for (int off = 32; off > 0; off >>= 1) v += __shfl_down(v, off);
    const int lane = threadIdx.x & 63;
    const int wid  = threadIdx.x >> 6;
    if (lane == 0) ws[wid] = v;
    __syncthreads();
    if (wid == 0) {
        v = (lane < 4) ? ws[lane] : 0.0f;
        #pragma unroll
        for (int off = 2; off > 0; off >>= 1) v += __shfl_down(v, off);
    }
    return v;  // valid in thread 0
}

// Derive per-particle packed data straight from the inputs (L2-hot, ~300 KB total):
//   a = (x, y, z, radius)   b = (s, c_last, type_bits, unused)
__device__ __forceinline__ void derive(int idx,
                                       const float* __restrict__ pos,
                                       const float* __restrict__ celltype,
                                       const float* __restrict__ cadherin,
                                       const float* __restrict__ radius,
                                       float4& a, float4& b) {
    const float x = pos[idx * 3 + 0];
    const float y = pos[idx * 3 + 1];
    const float z = pos[idx * 3 + 2];
    const float r = radius[idx];
    float s = 0.0f;
    int   t = 0;
    float best = -1.0f;
    #pragma unroll
    for (int k = 0; k < NTYPE; ++k) {
        const float c = celltype[idx * NTYPE + k];
        s += c * cadherin[idx * (NTYPE + 1) + k];
        if (c > best) { best = c; t = k; }
    }
    const float clast = cadherin[idx * (NTYPE + 1) + NTYPE];
    a = make_float4(x, y, z, r);
    b = make_float4(s, clast, __int_as_float(t), 0.0f);
}

// __launch_bounds__(256, 8): force VGPR <= 64 so 8 blocks/CU are resident ->
// 2048 >= 1536 blocks -> whole grid co-resident -> consumer spin cannot deadlock.
__global__ void __launch_bounds__(TILE_I, 8)
fused_kernel(const float* __restrict__ pos,
             const float* __restrict__ celltype,
             const float* __restrict__ cadherin,
             const float* __restrict__ radius,
             unsigned long long* __restrict__ slots,
             float* __restrict__ out) {
    __shared__ float4 sA[TILE_J];
    __shared__ float4 sB[TILE_J];

    const int ib  = blockIdx.x;
    const int jb  = blockIdx.y;
    const int i   = ib * TILE_I + threadIdx.x;
    const int jg0 = jb * TILE_J;

    if (threadIdx.x < TILE_J) {
        float4 a, b;
        derive(jg0 + (int)threadIdx.x, pos, celltype, cadherin, radius, a, b);
        sA[threadIdx.x] = a;
        sB[threadIdx.x] = b;
    }
    float4 ai, bi;
    derive(i, pos, celltype, cadherin, radius, ai, bi);
    const int   ti = __float_as_int(bi.z);
    const float si = bi.x;

    __syncthreads();

    float acc = 0.0f;
    #pragma unroll 8
    for (int jj = 0; jj < TILE_J; ++jj) {
        const float4 aj = sA[jj];
        const float dx = ai.x - aj.x;
        const float dy = ai.y - aj.y;
        const float dz = ai.z - aj.z;
        const float dr2 = dx * dx + dy * dy + dz * dz;
        if (dr2 < RC2) {                      // r >= cutoff contributes exactly 0
            const float r = (dr2 > 0.0f) ? sqrtf(dr2) : 1.0f;  // diagonal included; removed below
            const float4 bj = sB[jj];
            const float sigma = ai.w + aj.w;
            const float e = __expf(-ALPHA * (r - sigma));
            const int   tj = __float_as_int(bj.z);
            float eps = (ti == tj) ? (si + bj.x) : (2.0f * bj.y);
            eps = EPS_MAX * eps + EPS_MIN;
            float cut;
            if (r < R_ONSET) {
                cut = 1.0f;
            } else {
                const float r2 = r * r;
                const float d  = RC2 - r2;
                cut = d * d * (RC2 + 2.0f * r2 - 3.0f * RO2) * INV_DENOM;
            }
            acc += eps * (e * e - 2.0f * e) * cut;
        }
    }

    // Subtract the self-interaction (computed above as the dr2==0 diagonal term):
    // r=1, cut=1, same-type eps; identical expression -> ~exact cancellation.
    if ((unsigned)(i - jg0) < (unsigned)TILE_J) {
        const float sigma = ai.w + ai.w;
        const float e = __expf(-ALPHA * (1.0f - sigma));
        float eps = si + si;
        eps = EPS_MAX * eps + EPS_MIN;
        acc -= eps * (e * e - 2.0f * e);
    }

    const float bsum = block_reduce_256(acc);

    // Producer: publish (tag | payload) in ONE device-scope 64-bit atomic.
    const int b = jb * NIB + ib;
    if (threadIdx.x == 0) {
        const unsigned long long packed =
            ((unsigned long long)MAGIC << 32) | (unsigned long long)__float_as_uint(bsum);
        atomicExch(&slots[b], packed);
    }

    // Consumer: block (0,0). Consume-and-clear in a SINGLE atomic per poll:
    // atomicExch returns the old value; a failed poll rewrites 0 (harmless),
    // a successful poll consumes the value and leaves the slot cleaned for
    // the next graph replay. Never discards a published value.
    if (ib == 0 && jb == 0) {
        __syncthreads();   // protect block_reduce's shared ws before reuse below
        float acc2 = 0.0f;
        for (int k = threadIdx.x; k < NPART; k += TILE_I) {
            unsigned long long v;
            int guard = 0;
            do {
                v = atomicExch(&slots[k], 0ull);
            } while ((unsigned)(v >> 32) != MAGIC && ++guard < (1 << 24));
            acc2 += __uint_as_float((unsigned)v);
        }
        const float total = block_reduce_256(acc2);
        if (threadIdx.x == 0) out[0] = 0.5f * total;
    }
}

extern "C" void kernel_launch(void* const* d_in, const int* in_sizes, int n_in,
                              void* d_out, int out_size, void* d_ws, size_t ws_size,
                              hipStream_t stream) {
    const float* pos      = (const float*)d_in[0];
    const float* celltype = (const float*)d_in[1];
    const float* cadherin = (const float*)d_in[2];
    const float* radius   = (const float*)d_in[3];
    float* out = (float*)d_out;
    unsigned long long* slots = (unsigned long long*)d_ws;   // NPART x u64

    dim3 grid(NIB, NJB);
    fused_kernel<<<grid, TILE_I, 0, stream>>>(pos, celltype, cadherin, radius, slots, out);
}